// Round 4
// baseline (1162.247 us; speedup 1.0000x reference)
//
#include <hip/hip_runtime.h>
#include <stdint.h>

typedef unsigned short u16;
typedef __bf16 bf16x8 __attribute__((ext_vector_type(8)));
typedef float f32x4 __attribute__((ext_vector_type(4)));

#define N_NODES 50000
#define N_EDGES 800000
#define LN_EPS 1e-5f

// pack 8 consecutive f32 -> uint4 of 8 bf16 (RNE via hw cvt)
__device__ __forceinline__ uint4 pack8(const float* __restrict__ p) {
    const float4 f0 = ((const float4*)p)[0];
    const float4 f1 = ((const float4*)p)[1];
    union { __bf16 b[8]; uint4 q; } t;
    t.b[0] = (__bf16)f0.x; t.b[1] = (__bf16)f0.y; t.b[2] = (__bf16)f0.z; t.b[3] = (__bf16)f0.w;
    t.b[4] = (__bf16)f1.x; t.b[5] = (__bf16)f1.y; t.b[6] = (__bf16)f1.z; t.b[7] = (__bf16)f1.w;
    return t.q;
}

// ---------------- weight pre-pack ----------------
__global__ void pack_weights(const float* __restrict__ w1e, const float* __restrict__ w2e,
                             const float* __restrict__ w1n, const float* __restrict__ w2n,
                             uint4* __restrict__ out)
{
    const int t = blockIdx.x * 256 + threadIdx.x;
    const float* W; int idx;
    if (t < 6144)       { W = w1e; idx = t; }
    else if (t < 8192)  { W = w2e; idx = t - 6144; }
    else if (t < 12288) { W = w1n; idx = t - 8192; }
    else                { W = w2n; idx = t - 12288; }
    const int lane = idx & 63;
    const int col16 = (idx >> 6) & 7;
    const int kb = idx >> 9;
    const int row0 = kb * 32 + (lane >> 4) * 8;
    const int col = col16 * 16 + (lane & 15);
    union { __bf16 b[8]; uint4 q; } v;
#pragma unroll
    for (int j = 0; j < 8; ++j) v.b[j] = (__bf16)W[(size_t)(row0 + j) * 128 + col];
    out[t] = v.q;
}

// ---------------- counting sort by receiver ----------------
__global__ void hist_kernel(const int* __restrict__ receivers, int* __restrict__ cnt) {
    const int e = blockIdx.x * 256 + threadIdx.x;
    if (e < N_EDGES) atomicAdd(&cnt[receivers[e]], 1);
}

__global__ void scan_kernel(const int* __restrict__ cnt, int* __restrict__ cursor) {
    __shared__ int sums[1024];
    const int t = threadIdx.x;
    const int CH = 49;                 // 1024*49 >= 50000
    const int base = t * CH;
    int s = 0;
#pragma unroll 1
    for (int i = 0; i < CH; ++i) { const int idx = base + i; if (idx < N_NODES) s += cnt[idx]; }
    sums[t] = s;
    __syncthreads();
    for (int off = 1; off < 1024; off <<= 1) {
        const int v = (t >= off) ? sums[t - off] : 0;
        __syncthreads();
        sums[t] += v;
        __syncthreads();
    }
    int run = sums[t] - s;             // exclusive start of my chunk
#pragma unroll 1
    for (int i = 0; i < CH; ++i) {
        const int idx = base + i;
        if (idx < N_NODES) { cursor[idx] = run; run += cnt[idx]; }
    }
}

__global__ void scatter_kernel(const int* __restrict__ receivers, int* __restrict__ cursor,
                               int* __restrict__ sorted_eid) {
    const int e = blockIdx.x * 256 + threadIdx.x;
    if (e < N_EDGES) {
        const int pos = atomicAdd(&cursor[receivers[e]], 1);
        sorted_eid[pos] = e;
    }
}

// ---------------- Edge MLP + segment-reduced scatter ----------------
// x tile: [part(0=send,1=recv,2=elat)][64 rows][128 bf16], 16B chunks,
// XOR-swizzled within each row: stored_chunk = chunk ^ (row&7).
// After L1, part0 is overlaid by h1; after LN, parts0-1 are overlaid by ln f32.
template<int SORTED>
__global__ __launch_bounds__(256, 3)
void edge_mlp_kernel(const float* __restrict__ node, const float* __restrict__ elat,
                     const int* __restrict__ senders, const int* __restrict__ receivers,
                     const int* __restrict__ sorted_eid,
                     const float* __restrict__ b1, const float* __restrict__ b2,
                     const float* __restrict__ gam, const float* __restrict__ bet,
                     const uint4* __restrict__ w1p, const uint4* __restrict__ w2p,
                     float* __restrict__ eout, float* __restrict__ aggr)
{
    __shared__ __align__(16) u16 x_lds[3 * 64 * 128];   // 48 KB
    __shared__ int rcv_s[64];
    __shared__ int eid_s[64];
    __shared__ float2 part[256];
    __shared__ float muv[64], rsv[64];

    float* lnf = (float*)x_lds;                         // f32 [64][128] overlay, parts 0-1

    const int tid = threadIdx.x;
    const int w = tid >> 6;
    const int lane = tid & 63;
    const int cl = lane & 15;
    const int q = lane >> 4;
    const int n_base = w * 32;

    float b1v[2], b2v[2], gv[2], bv[2];
#pragma unroll
    for (int n = 0; n < 2; ++n) {
        const int c = n_base + n * 16 + cl;
        b1v[n] = b1[c]; b2v[n] = b2[c];
        gv[n]  = gam[c]; bv[n] = bet[c];
    }

    for (int tile = blockIdx.x; tile < N_EDGES / 64; tile += gridDim.x) {
        const int base = tile * 64;

        // ---- gather + f32->bf16 convert ----
        {
            const int ch = tid & 15;
            const int r0 = tid >> 4;
#pragma unroll
            for (int gp = 0; gp < 4; ++gp) {
                const int row = gp * 16 + r0;
                const int rx = row & 7;
                const int eid = SORTED ? sorted_eid[base + row] : (base + row);
                const int sn = senders[eid];
                const int rc = receivers[eid];
                if (ch == 0) { rcv_s[row] = rc; eid_s[row] = eid; }
                uint4* dst = (uint4*)x_lds + row * 16;
                dst[ch ^ rx]          = pack8(node + (size_t)sn * 128 + ch * 8);
                dst[1024 + (ch ^ rx)] = pack8(node + (size_t)rc * 128 + ch * 8);
                dst[2048 + (ch ^ rx)] = pack8(elat + (size_t)eid * 128 + ch * 8);
            }
        }
        __syncthreads();  // A: x tile + rcv/eid ready

        // ---- layer 1: [64,384] x [384,128], weights streamed ----
        f32x4 acc[4][2];
#pragma unroll
        for (int m = 0; m < 4; ++m)
#pragma unroll
            for (int n = 0; n < 2; ++n)
#pragma unroll
                for (int r = 0; r < 4; ++r) acc[m][n][r] = 0.f;

        uint4 wreg[14][2];
#pragma unroll
        for (int kb = 0; kb < 2; ++kb)
#pragma unroll
            for (int n = 0; n < 2; ++n)
                wreg[kb][n] = w1p[(kb * 8 + w * 2 + n) * 64 + lane];

#pragma unroll
        for (int kb = 0; kb < 12; ++kb) {
            if (kb + 2 < 12) {
#pragma unroll
                for (int n = 0; n < 2; ++n)
                    wreg[kb + 2][n] = w1p[((kb + 2) * 8 + w * 2 + n) * 64 + lane];
            }
            const int p = kb >> 2, k2 = kb & 3;
            bf16x8 a[4];
#pragma unroll
            for (int m = 0; m < 4; ++m) {
                const int row = m * 16 + cl;
                a[m] = __builtin_bit_cast(bf16x8,
                    ((const uint4*)x_lds)[p * 1024 + row * 16 + ((k2 * 4 + q) ^ (row & 7))]);
            }
#pragma unroll
            for (int m = 0; m < 4; ++m)
#pragma unroll
                for (int n = 0; n < 2; ++n)
                    acc[m][n] = __builtin_amdgcn_mfma_f32_16x16x32_bf16(
                        a[m], __builtin_bit_cast(bf16x8, wreg[kb][n]), acc[m][n], 0, 0, 0);
        }

        // prefetch all W2 fragments
        uint4 w2reg[4][2];
#pragma unroll
        for (int kb = 0; kb < 4; ++kb)
#pragma unroll
            for (int n = 0; n < 2; ++n)
                w2reg[kb][n] = w2p[(kb * 8 + w * 2 + n) * 64 + lane];

        __syncthreads();  // B: all waves done reading part0 before h overlay

        // relu + bias, h1 -> part0 region (swizzled)
        {
            __bf16* hb = (__bf16*)x_lds;
#pragma unroll
            for (int m = 0; m < 4; ++m)
#pragma unroll
                for (int n = 0; n < 2; ++n)
#pragma unroll
                    for (int r = 0; r < 4; ++r) {
                        const int row = m * 16 + q * 4 + r;
                        const int col = n_base + n * 16 + cl;
                        hb[row * 128 + (((col >> 3) ^ (row & 7)) << 3) + (col & 7)] =
                            (__bf16)fmaxf(acc[m][n][r] + b1v[n], 0.f);
                    }
        }
        __syncthreads();  // C: h ready

        // ---- layer 2: [64,128] x [128,128] ----
#pragma unroll
        for (int m = 0; m < 4; ++m)
#pragma unroll
            for (int n = 0; n < 2; ++n)
#pragma unroll
                for (int r = 0; r < 4; ++r) acc[m][n][r] = 0.f;
#pragma unroll
        for (int kb = 0; kb < 4; ++kb) {
            bf16x8 a[4];
#pragma unroll
            for (int m = 0; m < 4; ++m) {
                const int row = m * 16 + cl;
                a[m] = __builtin_bit_cast(bf16x8,
                    ((const uint4*)x_lds)[row * 16 + ((kb * 4 + q) ^ (row & 7))]);
            }
#pragma unroll
            for (int m = 0; m < 4; ++m)
#pragma unroll
                for (int n = 0; n < 2; ++n)
                    acc[m][n] = __builtin_amdgcn_mfma_f32_16x16x32_bf16(
                        a[m], __builtin_bit_cast(bf16x8, w2reg[kb][n]), acc[m][n], 0, 0, 0);
        }

#pragma unroll
        for (int m = 0; m < 4; ++m)
#pragma unroll
            for (int n = 0; n < 2; ++n)
#pragma unroll
                for (int r = 0; r < 4; ++r)
                    acc[m][n][r] = fmaxf(acc[m][n][r] + b2v[n], 0.f);

        // per-row partial sums for LN
#pragma unroll
        for (int m = 0; m < 4; ++m)
#pragma unroll
            for (int r = 0; r < 4; ++r) {
                float s  = acc[m][0][r] + acc[m][1][r];
                float ss = acc[m][0][r] * acc[m][0][r] + acc[m][1][r] * acc[m][1][r];
#pragma unroll
                for (int off = 1; off < 16; off <<= 1) {
                    s  += __shfl_xor(s, off, 64);
                    ss += __shfl_xor(ss, off, 64);
                }
                if (cl == 0) part[w * 64 + m * 16 + q * 4 + r] = make_float2(s, ss);
            }
        __syncthreads();  // D: also guarantees all waves finished L2 MFMA (part0 dead)
        if (tid < 64) {
            float s = 0.f, ss = 0.f;
#pragma unroll
            for (int ww = 0; ww < 4; ++ww) { const float2 pp = part[ww * 64 + tid]; s += pp.x; ss += pp.y; }
            const float mu = s * (1.f / 128.f);
            const float var = ss * (1.f / 128.f) - mu * mu;
            muv[tid] = mu;
            rsv[tid] = rsqrtf(var + LN_EPS);
        }
        __syncthreads();  // E

        // ---- LN: stage ln f32 to LDS (parts0-1), write eout (+elat residual) ----
#pragma unroll
        for (int m = 0; m < 4; ++m)
#pragma unroll
            for (int r = 0; r < 4; ++r) {
                const int row = m * 16 + q * 4 + r;
                const float mu = muv[row];
                const float rs = rsv[row];
                float* orow = eout + (size_t)eid_s[row] * 128;
#pragma unroll
                for (int n = 0; n < 2; ++n) {
                    const int col = n_base + n * 16 + cl;
                    const float ln = (acc[m][n][r] - mu) * rs * gv[n] + bv[n];
                    lnf[row * 128 + col] = ln;
                    const float e = (float)((__bf16*)x_lds)[16384 + row * 128 + (((col >> 3) ^ (row & 7)) << 3) + (col & 7)];
                    orow[col] = ln + e;
                }
            }
        __syncthreads();  // G: ln staged

        // ---- segment reduce over sorted receivers ----
        {
            const int c = tid & 127;
            const int h = tid >> 7;
            const int rstart = h * 32, rend = rstart + 32;
            float sacc = 0.f; int flushed = 0;
#pragma unroll 1
            for (int r = rstart; r < rend; ++r) {
                sacc += lnf[r * 128 + c];
                const int rc = rcv_s[r];
                const bool last = (r == 63);
                const bool bnd = last || (rc != rcv_s[r + 1]);
                if (bnd) {
                    float* dst = &aggr[(size_t)rc * 128 + c];
                    // interior segment of a globally-sorted run: sole writer -> plain store
                    if (SORTED && !last && flushed) *dst = sacc;
                    else atomicAdd(dst, sacc);
                    sacc = 0.f; flushed = 1;
                }
            }
            if (sacc != 0.f)  // pending run continuing past half boundary
                atomicAdd(&aggr[(size_t)rcv_s[rend - 1] * 128 + c], sacc);
        }
        __syncthreads();  // F: protect LDS before next gather
    }
}

// ---------------- Node MLP ----------------
__global__ __launch_bounds__(256, 4)
void node_mlp_kernel(const float* __restrict__ node, const float* __restrict__ aggr,
                     const float* __restrict__ b1, const float* __restrict__ b2,
                     const float* __restrict__ gam, const float* __restrict__ bet,
                     const uint4* __restrict__ w1p, const uint4* __restrict__ w2p,
                     float* __restrict__ nout)
{
    __shared__ __align__(16) u16 x_lds[2 * 64 * 128];   // 32 KB
    __shared__ float2 part[256];
    __shared__ float muv[64], rsv[64];

    const int tid = threadIdx.x;
    const int w = tid >> 6;
    const int lane = tid & 63;
    const int cl = lane & 15;
    const int q = lane >> 4;
    const int n_base = w * 32;

    float b1v[2], b2v[2], gv[2], bv[2];
#pragma unroll
    for (int n = 0; n < 2; ++n) {
        const int c = n_base + n * 16 + cl;
        b1v[n] = b1[c]; b2v[n] = b2[c];
        gv[n]  = gam[c]; bv[n] = bet[c];
    }

    const int ntiles = (N_NODES + 63) / 64;
    for (int tile = blockIdx.x; tile < ntiles; tile += gridDim.x) {
        const int base = tile * 64;

        // ---- gather (contiguous rows; f32 -> bf16) ----
        {
            const int ch = tid & 15;
            const int r0 = tid >> 4;
#pragma unroll
            for (int gp = 0; gp < 4; ++gp) {
                const int row = gp * 16 + r0;
                const int rx = row & 7;
                int gn = base + row;
                if (gn >= N_NODES) gn = N_NODES - 1;
                uint4* dst = (uint4*)x_lds + row * 16;
                dst[ch ^ rx]          = pack8(node + (size_t)gn * 128 + ch * 8);
                dst[1024 + (ch ^ rx)] = pack8(aggr + (size_t)gn * 128 + ch * 8);
            }
        }
        __syncthreads();  // A

        // ---- layer 1: [64,256] x [256,128] ----
        f32x4 acc[4][2];
#pragma unroll
        for (int m = 0; m < 4; ++m)
#pragma unroll
            for (int n = 0; n < 2; ++n)
#pragma unroll
                for (int r = 0; r < 4; ++r) acc[m][n][r] = 0.f;

        uint4 wreg[10][2];
#pragma unroll
        for (int kb = 0; kb < 2; ++kb)
#pragma unroll
            for (int n = 0; n < 2; ++n)
                wreg[kb][n] = w1p[(kb * 8 + w * 2 + n) * 64 + lane];

#pragma unroll
        for (int kb = 0; kb < 8; ++kb) {
            if (kb + 2 < 8) {
#pragma unroll
                for (int n = 0; n < 2; ++n)
                    wreg[kb + 2][n] = w1p[((kb + 2) * 8 + w * 2 + n) * 64 + lane];
            }
            const int p = kb >> 2, k2 = kb & 3;
            bf16x8 a[4];
#pragma unroll
            for (int m = 0; m < 4; ++m) {
                const int row = m * 16 + cl;
                a[m] = __builtin_bit_cast(bf16x8,
                    ((const uint4*)x_lds)[p * 1024 + row * 16 + ((k2 * 4 + q) ^ (row & 7))]);
            }
#pragma unroll
            for (int m = 0; m < 4; ++m)
#pragma unroll
                for (int n = 0; n < 2; ++n)
                    acc[m][n] = __builtin_amdgcn_mfma_f32_16x16x32_bf16(
                        a[m], __builtin_bit_cast(bf16x8, wreg[kb][n]), acc[m][n], 0, 0, 0);
        }

        uint4 w2reg[4][2];
#pragma unroll
        for (int kb = 0; kb < 4; ++kb)
#pragma unroll
            for (int n = 0; n < 2; ++n)
                w2reg[kb][n] = w2p[(kb * 8 + w * 2 + n) * 64 + lane];

        __syncthreads();  // B

        {
            __bf16* hb = (__bf16*)(x_lds + 8192);  // part1 region
#pragma unroll
            for (int m = 0; m < 4; ++m)
#pragma unroll
                for (int n = 0; n < 2; ++n)
#pragma unroll
                    for (int r = 0; r < 4; ++r) {
                        const int row = m * 16 + q * 4 + r;
                        const int col = n_base + n * 16 + cl;
                        hb[row * 128 + (((col >> 3) ^ (row & 7)) << 3) + (col & 7)] =
                            (__bf16)fmaxf(acc[m][n][r] + b1v[n], 0.f);
                    }
        }
        __syncthreads();  // C

        // ---- layer 2 ----
#pragma unroll
        for (int m = 0; m < 4; ++m)
#pragma unroll
            for (int n = 0; n < 2; ++n)
#pragma unroll
                for (int r = 0; r < 4; ++r) acc[m][n][r] = 0.f;
#pragma unroll
        for (int kb = 0; kb < 4; ++kb) {
            bf16x8 a[4];
#pragma unroll
            for (int m = 0; m < 4; ++m) {
                const int row = m * 16 + cl;
                a[m] = __builtin_bit_cast(bf16x8,
                    ((const uint4*)x_lds)[1024 + row * 16 + ((kb * 4 + q) ^ (row & 7))]);
            }
#pragma unroll
            for (int m = 0; m < 4; ++m)
#pragma unroll
                for (int n = 0; n < 2; ++n)
                    acc[m][n] = __builtin_amdgcn_mfma_f32_16x16x32_bf16(
                        a[m], __builtin_bit_cast(bf16x8, w2reg[kb][n]), acc[m][n], 0, 0, 0);
        }
#pragma unroll
        for (int m = 0; m < 4; ++m)
#pragma unroll
            for (int n = 0; n < 2; ++n)
#pragma unroll
                for (int r = 0; r < 4; ++r)
                    acc[m][n][r] = fmaxf(acc[m][n][r] + b2v[n], 0.f);

#pragma unroll
        for (int m = 0; m < 4; ++m)
#pragma unroll
            for (int r = 0; r < 4; ++r) {
                float s  = acc[m][0][r] + acc[m][1][r];
                float ss = acc[m][0][r] * acc[m][0][r] + acc[m][1][r] * acc[m][1][r];
#pragma unroll
                for (int off = 1; off < 16; off <<= 1) {
                    s  += __shfl_xor(s, off, 64);
                    ss += __shfl_xor(ss, off, 64);
                }
                if (cl == 0) part[w * 64 + m * 16 + q * 4 + r] = make_float2(s, ss);
            }
        __syncthreads();  // D
        if (tid < 64) {
            float s = 0.f, ss = 0.f;
#pragma unroll
            for (int ww = 0; ww < 4; ++ww) { const float2 pp = part[ww * 64 + tid]; s += pp.x; ss += pp.y; }
            const float mu = s * (1.f / 128.f);
            const float var = ss * (1.f / 128.f) - mu * mu;
            muv[tid] = mu;
            rsv[tid] = rsqrtf(var + LN_EPS);
        }
        __syncthreads();  // E

        // ---- LN + residual(part0) + guarded f32 writeout ----
#pragma unroll
        for (int m = 0; m < 4; ++m)
#pragma unroll
            for (int r = 0; r < 4; ++r) {
                const int row = m * 16 + q * 4 + r;
                if (base + row < N_NODES) {
                    const float mu = muv[row];
                    const float rs = rsv[row];
                    float* orow = nout + (size_t)(base + row) * 128;
#pragma unroll
                    for (int n = 0; n < 2; ++n) {
                        const int col = n_base + n * 16 + cl;
                        const float ln = (acc[m][n][r] - mu) * rs * gv[n] + bv[n];
                        const float e = (float)((__bf16*)x_lds)[row * 128 + (((col >> 3) ^ (row & 7)) << 3) + (col & 7)];
                        orow[col] = ln + e;
                    }
                }
            }
        __syncthreads();  // F
    }
}

extern "C" void kernel_launch(void* const* d_in, const int* in_sizes, int n_in,
                              void* d_out, int out_size, void* d_ws, size_t ws_size,
                              hipStream_t stream) {
    (void)in_sizes; (void)n_in; (void)out_size;
    const float* node = (const float*)d_in[0];
    const float* elat = (const float*)d_in[1];
    const int* senders = (const int*)d_in[2];
    const int* receivers = (const int*)d_in[3];
    const float* me_w1 = (const float*)d_in[4];
    const float* me_b1 = (const float*)d_in[5];
    const float* me_w2 = (const float*)d_in[6];
    const float* me_b2 = (const float*)d_in[7];
    const float* me_g  = (const float*)d_in[8];
    const float* me_be = (const float*)d_in[9];
    const float* nf_w1 = (const float*)d_in[10];
    const float* nf_b1 = (const float*)d_in[11];
    const float* nf_w2 = (const float*)d_in[12];
    const float* nf_b2 = (const float*)d_in[13];
    const float* nf_g  = (const float*)d_in[14];
    const float* nf_be = (const float*)d_in[15];

    float* out_nodes = (float*)d_out;
    float* out_edges = out_nodes + (size_t)N_NODES * 128;

    // ws layout (all offsets 16B-aligned)
    char* ws = (char*)d_ws;
    const size_t off_aggr   = 0;
    const size_t off_wpack  = off_aggr  + (size_t)N_NODES * 128 * sizeof(float);  // 25,600,000
    const size_t off_cnt    = off_wpack + 14336 * sizeof(uint4);                  // +229,376
    const size_t off_cursor = off_cnt   + (size_t)N_NODES * sizeof(int);          // +200,000
    const size_t off_sorted = off_cursor+ (size_t)N_NODES * sizeof(int);          // +200,000
    const size_t need_full  = off_sorted+ (size_t)N_EDGES * sizeof(int);          // +3,200,000
    const size_t need_min   = off_cnt;
    if (ws_size < need_min) return;

    float* aggr   = (float*)(ws + off_aggr);
    uint4* wpack  = (uint4*)(ws + off_wpack);
    int*   cnt    = (int*)(ws + off_cnt);
    int*   cursor = (int*)(ws + off_cursor);
    int*   sorted = (int*)(ws + off_sorted);
    const bool use_sort = (ws_size >= need_full);

    hipMemsetAsync(aggr, 0, (size_t)N_NODES * 128 * sizeof(float), stream);
    pack_weights<<<56, 256, 0, stream>>>(me_w1, me_w2, nf_w1, nf_w2, wpack);

    if (use_sort) {
        hipMemsetAsync(cnt, 0, (size_t)N_NODES * sizeof(int), stream);
        hist_kernel<<<(N_EDGES + 255) / 256, 256, 0, stream>>>(receivers, cnt);
        scan_kernel<<<1, 1024, 0, stream>>>(cnt, cursor);
        scatter_kernel<<<(N_EDGES + 255) / 256, 256, 0, stream>>>(receivers, cursor, sorted);
        edge_mlp_kernel<1><<<768, 256, 0, stream>>>(node, elat, senders, receivers, sorted,
                                                    me_b1, me_b2, me_g, me_be,
                                                    wpack, wpack + 6144,
                                                    out_edges, aggr);
    } else {
        edge_mlp_kernel<0><<<768, 256, 0, stream>>>(node, elat, senders, receivers, nullptr,
                                                    me_b1, me_b2, me_g, me_be,
                                                    wpack, wpack + 6144,
                                                    out_edges, aggr);
    }
    node_mlp_kernel<<<782, 256, 0, stream>>>(node, aggr,
                                             nf_b1, nf_b2, nf_g, nf_be,
                                             wpack + 8192, wpack + 12288,
                                             out_nodes);
}

// Round 5
// 1117.086 us; speedup vs baseline: 1.0404x; 1.0404x over previous
//
#include <hip/hip_runtime.h>
#include <stdint.h>

typedef unsigned short u16;
typedef __bf16 bf16x8 __attribute__((ext_vector_type(8)));
typedef float f32x4 __attribute__((ext_vector_type(4)));

#define N_NODES 50000
#define N_EDGES 800000
#define NTILES  (N_EDGES / 64)
#define LN_EPS 1e-5f

// pack 8 consecutive f32 -> uint4 of 8 bf16 (RNE via hw cvt)
__device__ __forceinline__ uint4 pack8(const float* __restrict__ p) {
    const float4 f0 = ((const float4*)p)[0];
    const float4 f1 = ((const float4*)p)[1];
    union { __bf16 b[8]; uint4 q; } t;
    t.b[0] = (__bf16)f0.x; t.b[1] = (__bf16)f0.y; t.b[2] = (__bf16)f0.z; t.b[3] = (__bf16)f0.w;
    t.b[4] = (__bf16)f1.x; t.b[5] = (__bf16)f1.y; t.b[6] = (__bf16)f1.z; t.b[7] = (__bf16)f1.w;
    return t.q;
}

// ---------------- weight pre-pack ----------------
__global__ void pack_weights(const float* __restrict__ w1e, const float* __restrict__ w2e,
                             const float* __restrict__ w1n, const float* __restrict__ w2n,
                             uint4* __restrict__ out)
{
    const int t = blockIdx.x * 256 + threadIdx.x;
    const float* W; int idx;
    if (t < 6144)       { W = w1e; idx = t; }
    else if (t < 8192)  { W = w2e; idx = t - 6144; }
    else if (t < 12288) { W = w1n; idx = t - 8192; }
    else                { W = w2n; idx = t - 12288; }
    const int lane = idx & 63;
    const int col16 = (idx >> 6) & 7;
    const int kb = idx >> 9;
    const int row0 = kb * 32 + (lane >> 4) * 8;
    const int col = col16 * 16 + (lane & 15);
    union { __bf16 b[8]; uint4 q; } v;
#pragma unroll
    for (int j = 0; j < 8; ++j) v.b[j] = (__bf16)W[(size_t)(row0 + j) * 128 + col];
    out[t] = v.q;
}

// ---------------- node table f32 -> bf16 (streaming) ----------------
__global__ void convert_node(const float* __restrict__ node, uint4* __restrict__ node_bf) {
    const int idx = blockIdx.x * 256 + threadIdx.x;   // 800,000 units of 8 elems
    node_bf[idx] = pack8(node + (size_t)(idx >> 4) * 128 + (idx & 15) * 8);
}

// ---------------- counting sort by receiver ----------------
__global__ void hist_kernel(const int* __restrict__ receivers, int* __restrict__ cnt) {
    const int e = blockIdx.x * 256 + threadIdx.x;
    if (e < N_EDGES) atomicAdd(&cnt[receivers[e]], 1);
}

#define SCAN_NB 196   // ceil(50000/256)
__global__ void scan1(const int* __restrict__ cnt, int* __restrict__ bsum) {
    __shared__ int wsum[4];
    const int i = blockIdx.x * 256 + threadIdx.x;
    int v = (i < N_NODES) ? cnt[i] : 0;
#pragma unroll
    for (int off = 1; off < 64; off <<= 1) v += __shfl_xor(v, off, 64);
    if ((threadIdx.x & 63) == 0) wsum[threadIdx.x >> 6] = v;
    __syncthreads();
    if (threadIdx.x == 0) bsum[blockIdx.x] = wsum[0] + wsum[1] + wsum[2] + wsum[3];
}
__global__ void scan2(const int* __restrict__ bsum, int* __restrict__ boff) {  // 1 block
    __shared__ int s[256];
    const int t = threadIdx.x;
    const int v = (t < SCAN_NB) ? bsum[t] : 0;
    s[t] = v; __syncthreads();
    for (int off = 1; off < 256; off <<= 1) {
        const int u = (t >= off) ? s[t - off] : 0;
        __syncthreads(); s[t] += u; __syncthreads();
    }
    if (t < SCAN_NB) boff[t] = s[t] - v;   // exclusive
}
__global__ void scan3(const int* __restrict__ cnt, const int* __restrict__ boff,
                      int* __restrict__ cursor) {
    __shared__ int s[256];
    const int i = blockIdx.x * 256 + threadIdx.x;
    const int t = threadIdx.x;
    const int v = (i < N_NODES) ? cnt[i] : 0;
    s[t] = v; __syncthreads();
    for (int off = 1; off < 256; off <<= 1) {
        const int u = (t >= off) ? s[t - off] : 0;
        __syncthreads(); s[t] += u; __syncthreads();
    }
    if (i < N_NODES) cursor[i] = boff[blockIdx.x] + s[t] - v;
}

__global__ void scatter_kernel(const int* __restrict__ senders, const int* __restrict__ receivers,
                               int* __restrict__ cursor,
                               int* __restrict__ sorted_eid, int* __restrict__ pos_of,
                               int* __restrict__ snd_sorted, int* __restrict__ rcv_sorted) {
    const int e = blockIdx.x * 256 + threadIdx.x;
    if (e < N_EDGES) {
        const int rc = receivers[e];
        const int pos = atomicAdd(&cursor[rc], 1);
        sorted_eid[pos] = e;
        pos_of[e] = pos;
        snd_sorted[pos] = senders[e];
        rcv_sorted[pos] = rc;
    }
}

// elat f32 (natural order, streaming read) -> bf16 rows at sorted position (scatter write)
__global__ void permute_elat(const float* __restrict__ elat, const int* __restrict__ pos_of,
                             uint4* __restrict__ elat_s) {
    const int idx = blockIdx.x * 256 + threadIdx.x;   // 12.8M units
    const int e = idx >> 4, ch = idx & 15;
    const int p = pos_of[e];
    elat_s[(size_t)p * 16 + ch] = pack8(elat + (size_t)e * 128 + ch * 8);
}

// ---------------- Edge MLP + segment-reduced scatter ----------------
// x tile: [part(0=send,1=recv,2=elat)][64 rows][128 bf16], 16B chunks,
// XOR-swizzled within each row: stored_chunk = chunk ^ (row&7).
// After L1, part0 is overlaid by h1; after LN, parts0-1 are overlaid by ln f32.
// SORTED=1: indices/elat pre-sorted by receiver (sequential); sender gather bf16.
// SORTED=0: natural order; elat f32 pack8; all-atomic aggregation.
template<int SORTED>
__global__ __launch_bounds__(256, 3)
void edge_mlp_kernel(const u16* __restrict__ node_bf, const float* __restrict__ elat,
                     const u16* __restrict__ elat_s,
                     const int* __restrict__ senders, const int* __restrict__ receivers,
                     const int* __restrict__ sorted_eid,
                     const int* __restrict__ snd_sorted, const int* __restrict__ rcv_sorted,
                     const float* __restrict__ b1, const float* __restrict__ b2,
                     const float* __restrict__ gam, const float* __restrict__ bet,
                     const uint4* __restrict__ w1p, const uint4* __restrict__ w2p,
                     float* __restrict__ eout, float* __restrict__ aggr)
{
    __shared__ __align__(16) u16 x_lds[3 * 64 * 128];   // 48 KB
    __shared__ int rcv_s[64];
    __shared__ int eid_s[64];
    __shared__ float2 part[256];
    __shared__ float muv[64], rsv[64];

    float* lnf = (float*)x_lds;                         // f32 [64][128] overlay, parts 0-1

    const int tid = threadIdx.x;
    const int w = tid >> 6;
    const int lane = tid & 63;
    const int cl = lane & 15;
    const int q = lane >> 4;
    const int n_base = w * 32;

    float b1v[2], b2v[2], gv[2], bv[2];
#pragma unroll
    for (int n = 0; n < 2; ++n) {
        const int c = n_base + n * 16 + cl;
        b1v[n] = b1[c]; b2v[n] = b2[c];
        gv[n]  = gam[c]; bv[n] = bet[c];
    }

    // XCD-chunked contiguous tile ranges: blocks on one XCD cover adjacent
    // sorted-receiver ranges -> receiver rows + aggr slice stay L2-local.
    const int nchunk = gridDim.x;                 // 768 (multiple of 8)
    const int chunk = (blockIdx.x & 7) * (nchunk >> 3) + (blockIdx.x >> 3);
    const int t_lo = (int)(((long long)chunk * NTILES) / nchunk);
    const int t_hi = (int)(((long long)(chunk + 1) * NTILES) / nchunk);

    for (int tile = t_lo; tile < t_hi; ++tile) {
        const int base = tile * 64;

        // ---- gather ----
        {
            const int ch = tid & 15;
            const int r0 = tid >> 4;
#pragma unroll
            for (int gp = 0; gp < 4; ++gp) {
                const int row = gp * 16 + r0;
                const int rx = row & 7;
                const int p = base + row;
                int sn, rc, eid;
                if (SORTED) {
                    sn = snd_sorted[p]; rc = rcv_sorted[p]; eid = sorted_eid[p];
                } else {
                    sn = senders[p]; rc = receivers[p]; eid = p;
                }
                if (ch == 0) { rcv_s[row] = rc; eid_s[row] = eid; }
                uint4* dst = (uint4*)x_lds + row * 16;
                dst[ch ^ rx]          = ((const uint4*)(node_bf + (size_t)sn * 128))[ch];
                dst[1024 + (ch ^ rx)] = ((const uint4*)(node_bf + (size_t)rc * 128))[ch];
                if (SORTED)
                    dst[2048 + (ch ^ rx)] = ((const uint4*)(elat_s + (size_t)p * 128))[ch];
                else
                    dst[2048 + (ch ^ rx)] = pack8(elat + (size_t)p * 128 + ch * 8);
            }
        }
        __syncthreads();  // A: x tile + rcv/eid ready

        // ---- layer 1: [64,384] x [384,128], weights streamed ----
        f32x4 acc[4][2];
#pragma unroll
        for (int m = 0; m < 4; ++m)
#pragma unroll
            for (int n = 0; n < 2; ++n)
#pragma unroll
                for (int r = 0; r < 4; ++r) acc[m][n][r] = 0.f;

        uint4 wreg[14][2];
#pragma unroll
        for (int kb = 0; kb < 2; ++kb)
#pragma unroll
            for (int n = 0; n < 2; ++n)
                wreg[kb][n] = w1p[(kb * 8 + w * 2 + n) * 64 + lane];

#pragma unroll
        for (int kb = 0; kb < 12; ++kb) {
            if (kb + 2 < 12) {
#pragma unroll
                for (int n = 0; n < 2; ++n)
                    wreg[kb + 2][n] = w1p[((kb + 2) * 8 + w * 2 + n) * 64 + lane];
            }
            const int p = kb >> 2, k2 = kb & 3;
            bf16x8 a[4];
#pragma unroll
            for (int m = 0; m < 4; ++m) {
                const int row = m * 16 + cl;
                a[m] = __builtin_bit_cast(bf16x8,
                    ((const uint4*)x_lds)[p * 1024 + row * 16 + ((k2 * 4 + q) ^ (row & 7))]);
            }
#pragma unroll
            for (int m = 0; m < 4; ++m)
#pragma unroll
                for (int n = 0; n < 2; ++n)
                    acc[m][n] = __builtin_amdgcn_mfma_f32_16x16x32_bf16(
                        a[m], __builtin_bit_cast(bf16x8, wreg[kb][n]), acc[m][n], 0, 0, 0);
        }

        // prefetch all W2 fragments
        uint4 w2reg[4][2];
#pragma unroll
        for (int kb = 0; kb < 4; ++kb)
#pragma unroll
            for (int n = 0; n < 2; ++n)
                w2reg[kb][n] = w2p[(kb * 8 + w * 2 + n) * 64 + lane];

        __syncthreads();  // B: all waves done reading part0 before h overlay

        // relu + bias, h1 -> part0 region (swizzled)
        {
            __bf16* hb = (__bf16*)x_lds;
#pragma unroll
            for (int m = 0; m < 4; ++m)
#pragma unroll
                for (int n = 0; n < 2; ++n)
#pragma unroll
                    for (int r = 0; r < 4; ++r) {
                        const int row = m * 16 + q * 4 + r;
                        const int col = n_base + n * 16 + cl;
                        hb[row * 128 + (((col >> 3) ^ (row & 7)) << 3) + (col & 7)] =
                            (__bf16)fmaxf(acc[m][n][r] + b1v[n], 0.f);
                    }
        }
        __syncthreads();  // C: h ready

        // ---- layer 2: [64,128] x [128,128] ----
#pragma unroll
        for (int m = 0; m < 4; ++m)
#pragma unroll
            for (int n = 0; n < 2; ++n)
#pragma unroll
                for (int r = 0; r < 4; ++r) acc[m][n][r] = 0.f;
#pragma unroll
        for (int kb = 0; kb < 4; ++kb) {
            bf16x8 a[4];
#pragma unroll
            for (int m = 0; m < 4; ++m) {
                const int row = m * 16 + cl;
                a[m] = __builtin_bit_cast(bf16x8,
                    ((const uint4*)x_lds)[row * 16 + ((kb * 4 + q) ^ (row & 7))]);
            }
#pragma unroll
            for (int m = 0; m < 4; ++m)
#pragma unroll
                for (int n = 0; n < 2; ++n)
                    acc[m][n] = __builtin_amdgcn_mfma_f32_16x16x32_bf16(
                        a[m], __builtin_bit_cast(bf16x8, w2reg[kb][n]), acc[m][n], 0, 0, 0);
        }

#pragma unroll
        for (int m = 0; m < 4; ++m)
#pragma unroll
            for (int n = 0; n < 2; ++n)
#pragma unroll
                for (int r = 0; r < 4; ++r)
                    acc[m][n][r] = fmaxf(acc[m][n][r] + b2v[n], 0.f);

        // per-row partial sums for LN
#pragma unroll
        for (int m = 0; m < 4; ++m)
#pragma unroll
            for (int r = 0; r < 4; ++r) {
                float s  = acc[m][0][r] + acc[m][1][r];
                float ss = acc[m][0][r] * acc[m][0][r] + acc[m][1][r] * acc[m][1][r];
#pragma unroll
                for (int off = 1; off < 16; off <<= 1) {
                    s  += __shfl_xor(s, off, 64);
                    ss += __shfl_xor(ss, off, 64);
                }
                if (cl == 0) part[w * 64 + m * 16 + q * 4 + r] = make_float2(s, ss);
            }
        __syncthreads();  // D
        if (tid < 64) {
            float s = 0.f, ss = 0.f;
#pragma unroll
            for (int ww = 0; ww < 4; ++ww) { const float2 pp = part[ww * 64 + tid]; s += pp.x; ss += pp.y; }
            const float mu = s * (1.f / 128.f);
            const float var = ss * (1.f / 128.f) - mu * mu;
            muv[tid] = mu;
            rsv[tid] = rsqrtf(var + LN_EPS);
        }
        __syncthreads();  // E

        // ---- LN: stage ln f32 to LDS (parts0-1), write eout (+elat residual) ----
#pragma unroll
        for (int m = 0; m < 4; ++m)
#pragma unroll
            for (int r = 0; r < 4; ++r) {
                const int row = m * 16 + q * 4 + r;
                const float mu = muv[row];
                const float rs = rsv[row];
                float* orow = eout + (size_t)eid_s[row] * 128;
#pragma unroll
                for (int n = 0; n < 2; ++n) {
                    const int col = n_base + n * 16 + cl;
                    const float ln = (acc[m][n][r] - mu) * rs * gv[n] + bv[n];
                    lnf[row * 128 + col] = ln;
                    const float e = (float)((__bf16*)x_lds)[16384 + row * 128 + (((col >> 3) ^ (row & 7)) << 3) + (col & 7)];
                    orow[col] = ln + e;
                }
            }
        __syncthreads();  // G: ln staged

        // ---- segment reduce over receivers (degenerates to atomics if unsorted) ----
        {
            const int c = tid & 127;
            const int h = tid >> 7;
            const int rstart = h * 32, rend = rstart + 32;
            float sacc = 0.f; int flushed = 0;
#pragma unroll 1
            for (int r = rstart; r < rend; ++r) {
                sacc += lnf[r * 128 + c];
                const int rc = rcv_s[r];
                const bool last = (r == 63);
                const bool bnd = last || (rc != rcv_s[r + 1]);
                if (bnd) {
                    float* dst = &aggr[(size_t)rc * 128 + c];
                    // interior segment of a globally-sorted run: sole writer -> plain store
                    if (SORTED && !last && flushed) *dst = sacc;
                    else atomicAdd(dst, sacc);
                    sacc = 0.f; flushed = 1;
                }
            }
            if (sacc != 0.f)  // pending run continuing past half boundary
                atomicAdd(&aggr[(size_t)rcv_s[rend - 1] * 128 + c], sacc);
        }
        __syncthreads();  // F: protect LDS before next gather
    }
}

// ---------------- Node MLP ----------------
__global__ __launch_bounds__(256, 4)
void node_mlp_kernel(const float* __restrict__ node, const float* __restrict__ aggr,
                     const float* __restrict__ b1, const float* __restrict__ b2,
                     const float* __restrict__ gam, const float* __restrict__ bet,
                     const uint4* __restrict__ w1p, const uint4* __restrict__ w2p,
                     float* __restrict__ nout)
{
    __shared__ __align__(16) u16 x_lds[2 * 64 * 128];   // 32 KB
    __shared__ float2 part[256];
    __shared__ float muv[64], rsv[64];

    const int tid = threadIdx.x;
    const int w = tid >> 6;
    const int lane = tid & 63;
    const int cl = lane & 15;
    const int q = lane >> 4;
    const int n_base = w * 32;

    float b1v[2], b2v[2], gv[2], bv[2];
#pragma unroll
    for (int n = 0; n < 2; ++n) {
        const int c = n_base + n * 16 + cl;
        b1v[n] = b1[c]; b2v[n] = b2[c];
        gv[n]  = gam[c]; bv[n] = bet[c];
    }

    const int ntiles = (N_NODES + 63) / 64;
    for (int tile = blockIdx.x; tile < ntiles; tile += gridDim.x) {
        const int base = tile * 64;

        // ---- gather (contiguous rows; f32 -> bf16) ----
        {
            const int ch = tid & 15;
            const int r0 = tid >> 4;
#pragma unroll
            for (int gp = 0; gp < 4; ++gp) {
                const int row = gp * 16 + r0;
                const int rx = row & 7;
                int gn = base + row;
                if (gn >= N_NODES) gn = N_NODES - 1;
                uint4* dst = (uint4*)x_lds + row * 16;
                dst[ch ^ rx]          = pack8(node + (size_t)gn * 128 + ch * 8);
                dst[1024 + (ch ^ rx)] = pack8(aggr + (size_t)gn * 128 + ch * 8);
            }
        }
        __syncthreads();  // A

        // ---- layer 1: [64,256] x [256,128] ----
        f32x4 acc[4][2];
#pragma unroll
        for (int m = 0; m < 4; ++m)
#pragma unroll
            for (int n = 0; n < 2; ++n)
#pragma unroll
                for (int r = 0; r < 4; ++r) acc[m][n][r] = 0.f;

        uint4 wreg[10][2];
#pragma unroll
        for (int kb = 0; kb < 2; ++kb)
#pragma unroll
            for (int n = 0; n < 2; ++n)
                wreg[kb][n] = w1p[(kb * 8 + w * 2 + n) * 64 + lane];

#pragma unroll
        for (int kb = 0; kb < 8; ++kb) {
            if (kb + 2 < 8) {
#pragma unroll
                for (int n = 0; n < 2; ++n)
                    wreg[kb + 2][n] = w1p[((kb + 2) * 8 + w * 2 + n) * 64 + lane];
            }
            const int p = kb >> 2, k2 = kb & 3;
            bf16x8 a[4];
#pragma unroll
            for (int m = 0; m < 4; ++m) {
                const int row = m * 16 + cl;
                a[m] = __builtin_bit_cast(bf16x8,
                    ((const uint4*)x_lds)[p * 1024 + row * 16 + ((k2 * 4 + q) ^ (row & 7))]);
            }
#pragma unroll
            for (int m = 0; m < 4; ++m)
#pragma unroll
                for (int n = 0; n < 2; ++n)
                    acc[m][n] = __builtin_amdgcn_mfma_f32_16x16x32_bf16(
                        a[m], __builtin_bit_cast(bf16x8, wreg[kb][n]), acc[m][n], 0, 0, 0);
        }

        uint4 w2reg[4][2];
#pragma unroll
        for (int kb = 0; kb < 4; ++kb)
#pragma unroll
            for (int n = 0; n < 2; ++n)
                w2reg[kb][n] = w2p[(kb * 8 + w * 2 + n) * 64 + lane];

        __syncthreads();  // B

        {
            __bf16* hb = (__bf16*)(x_lds + 8192);  // part1 region
#pragma unroll
            for (int m = 0; m < 4; ++m)
#pragma unroll
                for (int n = 0; n < 2; ++n)
#pragma unroll
                    for (int r = 0; r < 4; ++r) {
                        const int row = m * 16 + q * 4 + r;
                        const int col = n_base + n * 16 + cl;
                        hb[row * 128 + (((col >> 3) ^ (row & 7)) << 3) + (col & 7)] =
                            (__bf16)fmaxf(acc[m][n][r] + b1v[n], 0.f);
                    }
        }
        __syncthreads();  // C

        // ---- layer 2 ----
#pragma unroll
        for (int m = 0; m < 4; ++m)
#pragma unroll
            for (int n = 0; n < 2; ++n)
#pragma unroll
                for (int r = 0; r < 4; ++r) acc[m][n][r] = 0.f;
#pragma unroll
        for (int kb = 0; kb < 4; ++kb) {
            bf16x8 a[4];
#pragma unroll
            for (int m = 0; m < 4; ++m) {
                const int row = m * 16 + cl;
                a[m] = __builtin_bit_cast(bf16x8,
                    ((const uint4*)x_lds)[1024 + row * 16 + ((kb * 4 + q) ^ (row & 7))]);
            }
#pragma unroll
            for (int m = 0; m < 4; ++m)
#pragma unroll
                for (int n = 0; n < 2; ++n)
                    acc[m][n] = __builtin_amdgcn_mfma_f32_16x16x32_bf16(
                        a[m], __builtin_bit_cast(bf16x8, w2reg[kb][n]), acc[m][n], 0, 0, 0);
        }
#pragma unroll
        for (int m = 0; m < 4; ++m)
#pragma unroll
            for (int n = 0; n < 2; ++n)
#pragma unroll
                for (int r = 0; r < 4; ++r)
                    acc[m][n][r] = fmaxf(acc[m][n][r] + b2v[n], 0.f);

#pragma unroll
        for (int m = 0; m < 4; ++m)
#pragma unroll
            for (int r = 0; r < 4; ++r) {
                float s  = acc[m][0][r] + acc[m][1][r];
                float ss = acc[m][0][r] * acc[m][0][r] + acc[m][1][r] * acc[m][1][r];
#pragma unroll
                for (int off = 1; off < 16; off <<= 1) {
                    s  += __shfl_xor(s, off, 64);
                    ss += __shfl_xor(ss, off, 64);
                }
                if (cl == 0) part[w * 64 + m * 16 + q * 4 + r] = make_float2(s, ss);
            }
        __syncthreads();  // D
        if (tid < 64) {
            float s = 0.f, ss = 0.f;
#pragma unroll
            for (int ww = 0; ww < 4; ++ww) { const float2 pp = part[ww * 64 + tid]; s += pp.x; ss += pp.y; }
            const float mu = s * (1.f / 128.f);
            const float var = ss * (1.f / 128.f) - mu * mu;
            muv[tid] = mu;
            rsv[tid] = rsqrtf(var + LN_EPS);
        }
        __syncthreads();  // E

        // ---- LN + residual(part0) + guarded f32 writeout ----
#pragma unroll
        for (int m = 0; m < 4; ++m)
#pragma unroll
            for (int r = 0; r < 4; ++r) {
                const int row = m * 16 + q * 4 + r;
                if (base + row < N_NODES) {
                    const float mu = muv[row];
                    const float rs = rsv[row];
                    float* orow = nout + (size_t)(base + row) * 128;
#pragma unroll
                    for (int n = 0; n < 2; ++n) {
                        const int col = n_base + n * 16 + cl;
                        const float ln = (acc[m][n][r] - mu) * rs * gv[n] + bv[n];
                        const float e = (float)((__bf16*)x_lds)[row * 128 + (((col >> 3) ^ (row & 7)) << 3) + (col & 7)];
                        orow[col] = ln + e;
                    }
                }
            }
        __syncthreads();  // F
    }
}

extern "C" void kernel_launch(void* const* d_in, const int* in_sizes, int n_in,
                              void* d_out, int out_size, void* d_ws, size_t ws_size,
                              hipStream_t stream) {
    (void)in_sizes; (void)n_in; (void)out_size;
    const float* node = (const float*)d_in[0];
    const float* elat = (const float*)d_in[1];
    const int* senders = (const int*)d_in[2];
    const int* receivers = (const int*)d_in[3];
    const float* me_w1 = (const float*)d_in[4];
    const float* me_b1 = (const float*)d_in[5];
    const float* me_w2 = (const float*)d_in[6];
    const float* me_b2 = (const float*)d_in[7];
    const float* me_g  = (const float*)d_in[8];
    const float* me_be = (const float*)d_in[9];
    const float* nf_w1 = (const float*)d_in[10];
    const float* nf_b1 = (const float*)d_in[11];
    const float* nf_w2 = (const float*)d_in[12];
    const float* nf_b2 = (const float*)d_in[13];
    const float* nf_g  = (const float*)d_in[14];
    const float* nf_be = (const float*)d_in[15];

    float* out_nodes = (float*)d_out;
    float* out_edges = out_nodes + (size_t)N_NODES * 128;

    // Scratch overlaid on the out_nodes region (free until node_mlp runs last):
    // node_bf 12.8MB | sorted_eid 3.2MB | pos_of 3.2MB | snd_sorted 3.2MB | rcv_sorted 3.2MB = 25.6MB exactly
    char* ob = (char*)d_out;
    u16* node_bf    = (u16*)ob;
    int* sorted_eid = (int*)(ob + 12800000);
    int* pos_of     = (int*)(ob + 16000000);
    int* snd_sorted = (int*)(ob + 19200000);
    int* rcv_sorted = (int*)(ob + 22400000);

    // ws layout
    char* ws = (char*)d_ws;
    const size_t off_aggr   = 0;
    const size_t off_wpack  = off_aggr  + (size_t)N_NODES * 128 * sizeof(float);  // 25,600,000
    const size_t off_cnt    = off_wpack + 14336 * sizeof(uint4);                  // 25,829,376
    const size_t off_cursor = off_cnt   + (size_t)N_NODES * sizeof(int);          // 26,029,376
    const size_t off_scan   = off_cursor+ (size_t)N_NODES * sizeof(int);          // 26,229,376
    const size_t off_elat_s = off_scan  + 4096;                                   // 26,233,472
    const size_t need_b     = off_cnt;
    const size_t need_a     = off_elat_s + (size_t)N_EDGES * 128 * sizeof(u16);   // 231,033,472
    if (ws_size < need_b) return;

    float* aggr   = (float*)(ws + off_aggr);
    uint4* wpack  = (uint4*)(ws + off_wpack);
    int*   cnt    = (int*)(ws + off_cnt);
    int*   cursor = (int*)(ws + off_cursor);
    int*   bsum   = (int*)(ws + off_scan);
    int*   boff   = (int*)(ws + off_scan + 2048);
    u16*   elat_s = (u16*)(ws + off_elat_s);
    const bool tier_a = (ws_size >= need_a);

    hipMemsetAsync(aggr, 0, (size_t)N_NODES * 128 * sizeof(float), stream);
    pack_weights<<<56, 256, 0, stream>>>(me_w1, me_w2, nf_w1, nf_w2, wpack);
    convert_node<<<3125, 256, 0, stream>>>(node, (uint4*)node_bf);

    if (tier_a) {
        hipMemsetAsync(cnt, 0, (size_t)N_NODES * sizeof(int), stream);
        hist_kernel<<<(N_EDGES + 255) / 256, 256, 0, stream>>>(receivers, cnt);
        scan1<<<SCAN_NB, 256, 0, stream>>>(cnt, bsum);
        scan2<<<1, 256, 0, stream>>>(bsum, boff);
        scan3<<<SCAN_NB, 256, 0, stream>>>(cnt, boff, cursor);
        scatter_kernel<<<(N_EDGES + 255) / 256, 256, 0, stream>>>(
            senders, receivers, cursor, sorted_eid, pos_of, snd_sorted, rcv_sorted);
        permute_elat<<<50000, 256, 0, stream>>>(elat, pos_of, (uint4*)elat_s);
        edge_mlp_kernel<1><<<768, 256, 0, stream>>>(node_bf, elat, elat_s,
                                                    senders, receivers,
                                                    sorted_eid, snd_sorted, rcv_sorted,
                                                    me_b1, me_b2, me_g, me_be,
                                                    wpack, wpack + 6144,
                                                    out_edges, aggr);
    } else {
        edge_mlp_kernel<0><<<768, 256, 0, stream>>>(node_bf, elat, elat_s,
                                                    senders, receivers,
                                                    sorted_eid, snd_sorted, rcv_sorted,
                                                    me_b1, me_b2, me_g, me_be,
                                                    wpack, wpack + 6144,
                                                    out_edges, aggr);
    }
    node_mlp_kernel<<<782, 256, 0, stream>>>(node, aggr,
                                             nf_b1, nf_b2, nf_g, nf_be,
                                             wpack + 8192, wpack + 12288,
                                             out_nodes);
}